// Round 14
// baseline (683.500 us; speedup 1.0000x reference)
//
#include <hip/hip_runtime.h>
#include <hip/hip_bf16.h>

typedef __attribute__((ext_vector_type(8))) short bf16x8;
typedef __attribute__((ext_vector_type(4))) float f32x4;

#define GLDS(g, l) \
  __builtin_amdgcn_global_load_lds((const __attribute__((address_space(1))) void*)(g), \
                                   (__attribute__((address_space(3))) void*)(l), 16, 0, 0)

#define MFMA_BF16 __builtin_amdgcn_mfma_f32_16x16x32_bf16

// ---------------- Kernel 1: X fp32 -> bf16 (proven) ----------------
__global__ __launch_bounds__(256) void k_cvt_bf16(const float* __restrict__ x,
                                                  __hip_bfloat16* __restrict__ y,
                                                  long n8) {
  long stride = (long)gridDim.x * blockDim.x;
  for (long i = (long)blockIdx.x * blockDim.x + threadIdx.x; i < n8; i += stride) {
    const float4* xin = reinterpret_cast<const float4*>(x) + i * 2;
    float4 v0 = xin[0];
    float4 v1 = xin[1];
    union { __hip_bfloat16 h[8]; int4 v; } o;
    o.h[0] = __float2bfloat16(v0.x);
    o.h[1] = __float2bfloat16(v0.y);
    o.h[2] = __float2bfloat16(v0.z);
    o.h[3] = __float2bfloat16(v0.w);
    o.h[4] = __float2bfloat16(v1.x);
    o.h[5] = __float2bfloat16(v1.y);
    o.h[6] = __float2bfloat16(v1.z);
    o.h[7] = __float2bfloat16(v1.w);
    *reinterpret_cast<int4*>(y + i * 8) = o.v;
  }
}

// ---------------- Kernel 2: assemble W bf16 (proven, low-traffic) ----------------
__global__ __launch_bounds__(256) void k_make_w(const float* __restrict__ L,
                                                const float* __restrict__ R,
                                                __hip_bfloat16* __restrict__ W) {
  const int bc = blockIdx.x;  // b*64 + c
  const int b = bc >> 6, c = bc & 63;
  const int d = threadIdx.x & 63;
  const int q = threadIdx.x >> 6;
  float Rr[8];
#pragma unroll
  for (int r = 0; r < 8; ++r)
    Rr[r] = R[(((size_t)(r * 64 + b) * 64 + c) << 6) + d];
#pragma unroll 4
  for (int a = q * 16; a < q * 16 + 16; ++a) {
    const float* Lp = L + (((size_t)(a * 64 + b) * 64 + c) << 3);
    float s = 0.f;
#pragma unroll
    for (int r = 0; r < 8; ++r) s = fmaf(Lp[r], Rr[r], s);
    W[((size_t)(a * 64 + b) << 12) + (c << 6) + d] = __float2bfloat16(s);
  }
}

// ---------------- Kernel 3: 128x256 bf16 GEMM, BK=32, 4 waves, 2 blocks/CU ----------
// Anti-phase design: 256-thread blocks, 48 KB LDS -> two independent blocks per CU,
// each SIMD hosts one wave from EACH block. Block A's barrier/LDS phases overlap
// block B's MFMA (m114 cross-wave co-schedule) without intra-block tricks.
// Swizzle (BK=32, 64B rows): slot = lk ^ ((lr>>1)&3); every 8 consecutive lanes hit
// 8 distinct mod-128 bank positions (row-parity x 4 slots). Sync = r12's proven
// TILE_SYNC (explicit pre-barrier lgkm0+vmcnt0), one per K-tile.
__global__ __launch_bounds__(256, 2) void k_gemm_bt(const __hip_bfloat16* __restrict__ A,
                                                    const __hip_bfloat16* __restrict__ B,
                                                    const float* __restrict__ bias,
                                                    float* __restrict__ C) {
  const int N = 4096, NT = 128;
  __shared__ char lds[49152];
  char* const sA = lds;          // 2 x 8192  : A tile [128 rows][64 B], swizzled
  char* const sB = lds + 16384;  // 2 x 16384 : B tile [256 rows][64 B], swizzled

  const int tid = threadIdx.x;
  const int lane = tid & 63;
  const int w = tid >> 6;  // wave 0..3 == wc (N quarter)

  // T1: bijective XCD swizzle (nwg = 2048, divisible by 8)
  const int orig = blockIdx.x;
  const int wg = (orig & 7) * 256 + (orig >> 3);
  const int gm0 = (wg >> 4) * 128;  // 128 M-blocks
  const int gn0 = (wg & 15) * 256;  // 16 N-blocks

  // ---- staging geometry ----
  // Lane source offset (row = l>>2 within 16-row group, slot g = (l&3)^((l>>3)&3)):
  const int aoff = ((lane >> 2) * 8192) + (((lane & 3) ^ ((lane >> 3) & 3)) << 4);
  const char* const Ab = (const char*)A + (size_t)gm0 * 8192;
  const char* const Bb = (const char*)B + (size_t)gn0 * 8192;

  // A: 2 loads/wave (16 rows each); B: 4 loads/wave. Dest wave-uniform + lane*16.
#define STAGE(BUF, T)                                                         \
  {                                                                           \
    _Pragma("unroll")                                                         \
    for (int j = 0; j < 2; ++j)                                               \
      GLDS(Ab + (size_t)(w * 2 + j) * 131072 + (T) * 64 + aoff,               \
           sA + (BUF) * 8192 + (w * 2 + j) * 1024);                           \
    _Pragma("unroll")                                                         \
    for (int j = 0; j < 4; ++j)                                               \
      GLDS(Bb + (size_t)(w * 4 + j) * 131072 + (T) * 64 + aoff,               \
           sB + (BUF) * 16384 + (w * 4 + j) * 1024);                          \
  }

  // ---- fragment-read geometry ----
  const int lr = lane & 15;
  const int lk = lane >> 4;                       // 0..3 (k-slot of 8 bf16)
  const int kslot = (lk ^ ((lr >> 1) & 3)) << 4;  // swizzled 16B slot (lane-const)
  const char* const rdA = sA + lr * 64 + kslot;
  const char* const rdB = sB + (w << 12) + lr * 64 + kslot;

#define PREF(BUF)                                                             \
  _Pragma("unroll")                                                           \
  for (int m = 0; m < 8; ++m)                                                 \
    a[m] = *(const bf16x8*)(rdA + (BUF) * 8192 + m * 1024);                   \
  _Pragma("unroll")                                                           \
  for (int n = 0; n < 4; ++n)                                                 \
    b[n] = *(const bf16x8*)(rdB + (BUF) * 16384 + n * 1024);

#define SBAR0 __builtin_amdgcn_sched_barrier(0)
// r12-proven tile boundary: per-wave drain (lds reads + vmem incl global_load_lds)
// BEFORE s_barrier -> collective certify-then-publish.
#define TILE_SYNC                                                             \
  asm volatile("s_waitcnt lgkmcnt(0) vmcnt(0)" ::: "memory");                 \
  SBAR0;                                                                      \
  __builtin_amdgcn_s_barrier();                                               \
  SBAR0;

  // epilogue coords (C/D 16x16 layout: col = lane&15, row = (lane>>4)*4 + j)
  const int er = gm0 + (lane >> 4) * 4;
  const int ec = gn0 + w * 64 + (lane & 15);

  f32x4 acc[8][4];
#pragma unroll
  for (int n = 0; n < 4; ++n) {
    const float bv = bias[ec + n * 16];
#pragma unroll
    for (int m = 0; m < 8; ++m) acc[m][n] = (f32x4){bv, bv, bv, bv};
  }

  bf16x8 a[8], b[4];

  // ---- prologue: stage tile 0 only; first TILE_SYNC certifies it ----
  STAGE(0, 0)

#define TILE(BUF, T)                                                          \
  {                                                                           \
    TILE_SYNC                                                                 \
    if ((T) + 1 < NT) STAGE((BUF) ^ 1, (T) + 1)                               \
    PREF(BUF)                                                                 \
    __builtin_amdgcn_s_setprio(1);                                            \
    _Pragma("unroll")                                                         \
    for (int m = 0; m < 8; ++m)                                               \
      _Pragma("unroll")                                                       \
      for (int n = 0; n < 4; ++n)                                             \
        acc[m][n] = MFMA_BF16(a[m], b[n], acc[m][n], 0, 0, 0);                \
    __builtin_amdgcn_s_setprio(0);                                            \
  }

  for (int t = 0; t < NT; t += 2) {
    TILE(0, t)
    TILE(1, t + 1)
  }
  asm volatile("s_waitcnt vmcnt(0) lgkmcnt(0)" ::: "memory");

  // ---- epilogue: C[row][col] = acc (bias pre-seeded) ----
#pragma unroll
  for (int n = 0; n < 4; ++n) {
    const int c = ec + n * 16;
#pragma unroll
    for (int m = 0; m < 8; ++m) {
#pragma unroll
      for (int j = 0; j < 4; ++j) {
        C[(size_t)(er + m * 16 + j) * N + c] = acc[m][n][j];
      }
    }
  }
}

extern "C" void kernel_launch(void* const* d_in, const int* in_sizes, int n_in,
                              void* d_out, int out_size, void* d_ws, size_t ws_size,
                              hipStream_t stream) {
  const float* x = (const float*)d_in[0];     // [8,2048,4096]
  const float* L = (const float*)d_in[1];     // [64,64,64,8]
  const float* R = (const float*)d_in[2];     // [8,64,64,64]
  const float* bias = (const float*)d_in[3];  // [4096]
  float* out = (float*)d_out;                 // [16384,4096]

  __hip_bfloat16* Wb = (__hip_bfloat16*)d_ws;                                    // 33.5 MB
  __hip_bfloat16* Xb = (__hip_bfloat16*)((char*)d_ws + (size_t)4096 * 4096 * 2); // 134 MB

  const long n8 = (long)16384 * 4096 / 8;
  k_cvt_bf16<<<4096, 256, 0, stream>>>(x, Xb, n8);
  k_make_w<<<4096, 256, 0, stream>>>(L, R, Wb);

  dim3 grid(2048);  // (16384/128) * (4096/256)
  k_gemm_bt<<<grid, 256, 0, stream>>>(Xb, Wb, bias, out);
}

// Round 15
// 559.822 us; speedup vs baseline: 1.2209x; 1.2209x over previous
//
#include <hip/hip_runtime.h>
#include <hip/hip_bf16.h>

typedef __attribute__((ext_vector_type(8))) short bf16x8;
typedef __attribute__((ext_vector_type(4))) float f32x4;

#define GLDS(g, l) \
  __builtin_amdgcn_global_load_lds((const __attribute__((address_space(1))) void*)(g), \
                                   (__attribute__((address_space(3))) void*)(l), 16, 0, 0)

#define MFMA_BF16 __builtin_amdgcn_mfma_f32_16x16x32_bf16

// ---------------- Kernel 1: fused X fp32->bf16 cvt + W assembly (r9/r10-proven) -------
__global__ __launch_bounds__(256) void k_prep(const float* __restrict__ x,
                                              __hip_bfloat16* __restrict__ y,
                                              const float* __restrict__ L,
                                              const float* __restrict__ R,
                                              __hip_bfloat16* __restrict__ W) {
  if (blockIdx.x < 4096) {
    // cvt: grid-stride over 8-element groups
    const long n8 = (long)16384 * 4096 / 8;
    const long stride = (long)4096 * 256;
    for (long i = (long)blockIdx.x * 256 + threadIdx.x; i < n8; i += stride) {
      const float4* xin = reinterpret_cast<const float4*>(x) + i * 2;
      float4 v0 = xin[0];
      float4 v1 = xin[1];
      union { __hip_bfloat16 h[8]; int4 v; } o;
      o.h[0] = __float2bfloat16(v0.x);
      o.h[1] = __float2bfloat16(v0.y);
      o.h[2] = __float2bfloat16(v0.z);
      o.h[3] = __float2bfloat16(v0.w);
      o.h[4] = __float2bfloat16(v1.x);
      o.h[5] = __float2bfloat16(v1.y);
      o.h[6] = __float2bfloat16(v1.z);
      o.h[7] = __float2bfloat16(v1.w);
      *reinterpret_cast<int4*>(y + i * 8) = o.v;
    }
  } else {
    // make_w: one block per (b,c) pair; reads L 2KB + R 2KB
    const int bc = blockIdx.x - 4096;  // b*64 + c
    const int b = bc >> 6, c = bc & 63;
    const int d = threadIdx.x & 63;
    const int q = threadIdx.x >> 6;
    float Rr[8];
#pragma unroll
    for (int r = 0; r < 8; ++r)
      Rr[r] = R[(((size_t)(r * 64 + b) * 64 + c) << 6) + d];
#pragma unroll 4
    for (int a = q * 16; a < q * 16 + 16; ++a) {
      const float* Lp = L + (((size_t)(a * 64 + b) * 64 + c) << 3);
      float s = 0.f;
#pragma unroll
      for (int r = 0; r < 8; ++r) s = fmaf(Lp[r], Rr[r], s);
      W[((size_t)(a * 64 + b) << 12) + (c << 6) + d] = __float2bfloat16(s);
    }
  }
}

// ---------------- Kernel 2: 256x256 bf16 GEMM (r12, session-best: 477us, 53% MfmaUtil)
// Fence-free phases (compiler-tracked ds_read->MFMA deps); ONE explicit tile boundary
// per K-tile: asm lgkm0+vmcnt0 drain BEFORE s_barrier (r5/r6/r11 race lessons), with
// sched_barrier brackets. T1 XCD swizzle + T2 XOR swizzle (0 conflicts) + T5 setprio.
// Bias pre-seeded into accumulators.
__global__ __launch_bounds__(512, 2) void k_gemm_bt(const __hip_bfloat16* __restrict__ A,
                                                    const __hip_bfloat16* __restrict__ B,
                                                    const float* __restrict__ bias,
                                                    float* __restrict__ C) {
  const int K = 4096, N = 4096, NT = 64;
  __shared__ char lds[131072];
  char* const sAc = lds;          // 2 x 32768: A tile [256][64] bf16, swizzled
  char* const sBc = lds + 65536;  // 2 x 32768

  const int tid = threadIdx.x;
  const int lane = tid & 63;
  const int wid = tid >> 6;
  const int wr = wid >> 2;    // 0..1 (M half)
  const int wc = wid & 3;     // 0..3 (N quarter)

  // T1: bijective XCD swizzle (nwg = 1024, divisible by 8)
  const int orig = blockIdx.x;
  const int wg = (orig & 7) * 128 + (orig >> 3);
  const int gm0 = (wg >> 4) * 256;
  const int gn0 = (wg & 15) * 256;

  // ---- staging geometry (pre-swizzled global source, linear LDS dest) ----
  const int crow = tid >> 3;
  const int scol = ((tid & 7) << 4) ^ ((crow & 7) << 4);
  const int voff = crow * 8192 + scol;
  const int wbase = (tid >> 6) << 10;
  const char* const Ab = (const char*)(A + (size_t)gm0 * K);
  const char* const Bb = (const char*)(B + (size_t)gn0 * K);

#define STAGEA(BUF, TS)                                                      \
  _Pragma("unroll")                                                          \
  for (int j = 0; j < 4; ++j)                                                \
    GLDS(Ab + (size_t)((TS) * 128 + j * 524288) + voff,                      \
         sAc + (BUF) * 32768 + j * 8192 + wbase);

#define STAGEB(BUF, TS)                                                      \
  _Pragma("unroll")                                                          \
  for (int j = 0; j < 4; ++j)                                                \
    GLDS(Bb + (size_t)((TS) * 128 + j * 524288) + voff,                      \
         sBc + (BUF) * 32768 + j * 8192 + wbase);

  // ---- fragment-read geometry (swizzled ds_read) ----
  const int lr = lane & 15;
  const int lk = lane >> 4;
  const int kx0 = (lk << 4) ^ ((lr & 7) << 4);
  const int kx1 = (64 + (lk << 4)) ^ ((lr & 7) << 4);
  const char* const rA0 = sAc + (((wr << 7) + lr) << 7) + kx0;
  const char* const rA1 = sAc + (((wr << 7) + lr) << 7) + kx1;
  const char* const rB0 = sBc + (((wc << 6) + lr) << 7) + kx0;
  const char* const rB1 = sBc + (((wc << 6) + lr) << 7) + kx1;

#define PREFA(DST, BUF, MOFS)                                                \
  _Pragma("unroll")                                                          \
  for (int m = 0; m < 4; ++m) {                                              \
    DST[m][0] = *(const bf16x8*)(rA0 + (BUF) * 32768 + ((MOFS) + m) * 2048); \
    DST[m][1] = *(const bf16x8*)(rA1 + (BUF) * 32768 + ((MOFS) + m) * 2048); \
  }

#define PREFB(DST, BUF, NOFS)                                                \
  _Pragma("unroll")                                                          \
  for (int n = 0; n < 2; ++n) {                                              \
    DST[n][0] = *(const bf16x8*)(rB0 + (BUF) * 32768 + ((NOFS) + n) * 2048); \
    DST[n][1] = *(const bf16x8*)(rB1 + (BUF) * 32768 + ((NOFS) + n) * 2048); \
  }

#define MFMA8X(AF, BF, MB, NB)                                               \
  _Pragma("unroll")                                                          \
  for (int m = 0; m < 4; ++m) {                                              \
    acc[(MB) + m][(NB) + 0] =                                                \
        MFMA_BF16(AF[m][0], BF[0][0], acc[(MB) + m][(NB) + 0], 0, 0, 0);     \
    acc[(MB) + m][(NB) + 0] =                                                \
        MFMA_BF16(AF[m][1], BF[0][1], acc[(MB) + m][(NB) + 0], 0, 0, 0);     \
    acc[(MB) + m][(NB) + 1] =                                                \
        MFMA_BF16(AF[m][0], BF[1][0], acc[(MB) + m][(NB) + 1], 0, 0, 0);     \
    acc[(MB) + m][(NB) + 1] =                                                \
        MFMA_BF16(AF[m][1], BF[1][1], acc[(MB) + m][(NB) + 1], 0, 0, 0);     \
  }

#define SBAR0 __builtin_amdgcn_sched_barrier(0)
#define TILE_SYNC                                                            \
  asm volatile("s_waitcnt lgkmcnt(0) vmcnt(0)" ::: "memory");                \
  SBAR0;                                                                     \
  __builtin_amdgcn_s_barrier();                                              \
  SBAR0;

  // epilogue coords (needed for bias-seeded acc)
  const int er = gm0 + (wr << 7) + ((lane >> 4) << 2);
  const int ec = gn0 + (wc << 6) + (lane & 15);

  f32x4 acc[8][4];
#pragma unroll
  for (int n = 0; n < 4; ++n) {
    const float bv = bias[ec + n * 16];
#pragma unroll
    for (int m = 0; m < 8; ++m) acc[m][n] = (f32x4){bv, bv, bv, bv};
  }

  bf16x8 aX[4][2], aY[4][2], b0[2][2], b2[2][2];

  // ---- prologue: stage tiles 0,1; explicit drain of tile 0; publish; first reads ----
  STAGEA(0, 0) STAGEB(0, 0) STAGEA(1, 1) STAGEB(1, 1)
  asm volatile("s_waitcnt vmcnt(8)" ::: "memory");
  SBAR0;
  __builtin_amdgcn_s_barrier();
  SBAR0;
  PREFA(aX, 0, 0) PREFB(b0, 0, 0)

  // Phase order per tile: P1(m03,n01,aX) P2(m47,n01,aY) P3(m03,n23,aX) P4(m47,n23,aY)
  // Prefetch: P1->aY=A47(t)  P2->b2=B23(t)  P3->b0=B01(t+1)  P4->aX=A03(t+1)
  // Staging:  P3: A(t+2)->BUF (post-sync);  P4: B(t+2)->BUF
#define TILE(BUF, T)                                                         \
  {                                                                          \
    const int tS = ((T) + 2 < NT) ? (T) + 2 : NT - 1;                        \
    /* P1 */                                                                 \
    PREFA(aY, BUF, 4)                                                        \
    __builtin_amdgcn_s_setprio(1);                                           \
    MFMA8X(aX, b0, 0, 0)                                                     \
    __builtin_amdgcn_s_setprio(0);                                           \
    /* P2 */                                                                 \
    PREFB(b2, BUF, 2)                                                        \
    __builtin_amdgcn_s_setprio(1);                                           \
    MFMA8X(aY, b0, 4, 0)                                                     \
    __builtin_amdgcn_s_setprio(0);                                           \
    /* P3: tile boundary (explicit certify-then-publish) */                  \
    TILE_SYNC                                                                \
    STAGEA(BUF, tS)                                                          \
    PREFB(b0, (BUF) ^ 1, 0)                                                  \
    __builtin_amdgcn_s_setprio(1);                                           \
    MFMA8X(aX, b2, 0, 2)                                                     \
    __builtin_amdgcn_s_setprio(0);                                           \
    /* P4 */                                                                 \
    STAGEB(BUF, tS)                                                          \
    PREFA(aX, (BUF) ^ 1, 0)                                                  \
    __builtin_amdgcn_s_setprio(1);                                           \
    MFMA8X(aY, b2, 4, 2)                                                     \
    __builtin_amdgcn_s_setprio(0);                                           \
  }

  for (int t = 0; t < NT; t += 2) {
    TILE(0, t)
    TILE(1, t + 1)
  }
  asm volatile("s_waitcnt vmcnt(0) lgkmcnt(0)" ::: "memory");

  // ---- epilogue: C[row][col] = acc (bias pre-seeded) ----
#pragma unroll
  for (int n = 0; n < 4; ++n) {
    const int c = ec + n * 16;
#pragma unroll
    for (int m = 0; m < 8; ++m) {
#pragma unroll
      for (int j = 0; j < 4; ++j) {
        C[(size_t)(er + m * 16 + j) * N + c] = acc[m][n][j];
      }
    }
  }
}

extern "C" void kernel_launch(void* const* d_in, const int* in_sizes, int n_in,
                              void* d_out, int out_size, void* d_ws, size_t ws_size,
                              hipStream_t stream) {
  const float* x = (const float*)d_in[0];     // [8,2048,4096]
  const float* L = (const float*)d_in[1];     // [64,64,64,8]
  const float* R = (const float*)d_in[2];     // [8,64,64,64]
  const float* bias = (const float*)d_in[3];  // [4096]
  float* out = (float*)d_out;                 // [16384,4096]

  __hip_bfloat16* Wb = (__hip_bfloat16*)d_ws;                                    // 33.5 MB
  __hip_bfloat16* Xb = (__hip_bfloat16*)((char*)d_ws + (size_t)4096 * 4096 * 2); // 134 MB

  k_prep<<<8192, 256, 0, stream>>>(x, Xb, L, R, Wb);

  dim3 grid(1024);  // (16384/256) * (4096/256)
  k_gemm_bt<<<grid, 512, 0, stream>>>(Xb, Wb, bias, out);
}

// Round 16
// 559.273 us; speedup vs baseline: 1.2221x; 1.0010x over previous
//
#include <hip/hip_runtime.h>
#include <hip/hip_bf16.h>

typedef __attribute__((ext_vector_type(8))) short bf16x8;
typedef __attribute__((ext_vector_type(4))) float f32x4;

#define GLDS(g, l) \
  __builtin_amdgcn_global_load_lds((const __attribute__((address_space(1))) void*)(g), \
                                   (__attribute__((address_space(3))) void*)(l), 16, 0, 0)

#define MFMA_BF16 __builtin_amdgcn_mfma_f32_16x16x32_bf16

// ---------------- Kernel 1: fused X fp32->bf16 cvt + W assembly (proven) -------------
__global__ __launch_bounds__(256) void k_prep(const float* __restrict__ x,
                                              __hip_bfloat16* __restrict__ y,
                                              const float* __restrict__ L,
                                              const float* __restrict__ R,
                                              __hip_bfloat16* __restrict__ W) {
  if (blockIdx.x < 4096) {
    // cvt: grid-stride over 8-element groups (memory-roofline bound, ~64 us)
    const long n8 = (long)16384 * 4096 / 8;
    const long stride = (long)4096 * 256;
    for (long i = (long)blockIdx.x * 256 + threadIdx.x; i < n8; i += stride) {
      const float4* xin = reinterpret_cast<const float4*>(x) + i * 2;
      float4 v0 = xin[0];
      float4 v1 = xin[1];
      union { __hip_bfloat16 h[8]; int4 v; } o;
      o.h[0] = __float2bfloat16(v0.x);
      o.h[1] = __float2bfloat16(v0.y);
      o.h[2] = __float2bfloat16(v0.z);
      o.h[3] = __float2bfloat16(v0.w);
      o.h[4] = __float2bfloat16(v1.x);
      o.h[5] = __float2bfloat16(v1.y);
      o.h[6] = __float2bfloat16(v1.z);
      o.h[7] = __float2bfloat16(v1.w);
      *reinterpret_cast<int4*>(y + i * 8) = o.v;
    }
  } else {
    // make_w: one block per (b,c) pair; reads L 2KB + R 2KB (L2/L3-resident)
    const int bc = blockIdx.x - 4096;  // b*64 + c
    const int b = bc >> 6, c = bc & 63;
    const int d = threadIdx.x & 63;
    const int q = threadIdx.x >> 6;
    float Rr[8];
#pragma unroll
    for (int r = 0; r < 8; ++r)
      Rr[r] = R[(((size_t)(r * 64 + b) * 64 + c) << 6) + d];
#pragma unroll 4
    for (int a = q * 16; a < q * 16 + 16; ++a) {
      const float* Lp = L + (((size_t)(a * 64 + b) * 64 + c) << 3);
      float s = 0.f;
#pragma unroll
      for (int r = 0; r < 8; ++r) s = fmaf(Lp[r], Rr[r], s);
      W[((size_t)(a * 64 + b) << 12) + (c << 6) + d] = __float2bfloat16(s);
    }
  }
}

// ---------------- Kernel 2: 256x256 bf16 GEMM (session-best structure) ----------------
// Fence-free phases (compiler-tracked ds_read->MFMA deps); ONE explicit tile boundary
// per K-tile: asm lgkm0+vmcnt0 drain BEFORE s_barrier (certify-then-publish; the
// r5/r6/r11 race lessons), sched_barrier brackets. T1 XCD swizzle + T2 XOR swizzle
// (0 bank conflicts) + T5 setprio. Bias pre-seeded into accumulators.
// Matrix-pipe-gap bound at 2 waves/SIMD: MfmaUtil ~55% == 2484 cyc MFMA / 4472 tile.
__global__ __launch_bounds__(512, 2) void k_gemm_bt(const __hip_bfloat16* __restrict__ A,
                                                    const __hip_bfloat16* __restrict__ B,
                                                    const float* __restrict__ bias,
                                                    float* __restrict__ C) {
  const int K = 4096, N = 4096, NT = 64;
  __shared__ char lds[131072];
  char* const sAc = lds;          // 2 x 32768: A tile [256][64] bf16, swizzled
  char* const sBc = lds + 65536;  // 2 x 32768

  const int tid = threadIdx.x;
  const int lane = tid & 63;
  const int wid = tid >> 6;
  const int wr = wid >> 2;    // 0..1 (M half)
  const int wc = wid & 3;     // 0..3 (N quarter)

  // T1: bijective XCD swizzle (nwg = 1024, divisible by 8)
  const int orig = blockIdx.x;
  const int wg = (orig & 7) * 128 + (orig >> 3);
  const int gm0 = (wg >> 4) * 256;
  const int gn0 = (wg & 15) * 256;

  // ---- staging geometry (pre-swizzled global source, linear LDS dest) ----
  const int crow = tid >> 3;
  const int scol = ((tid & 7) << 4) ^ ((crow & 7) << 4);
  const int voff = crow * 8192 + scol;
  const int wbase = (tid >> 6) << 10;
  const char* const Ab = (const char*)(A + (size_t)gm0 * K);
  const char* const Bb = (const char*)(B + (size_t)gn0 * K);

#define STAGEA(BUF, TS)                                                      \
  _Pragma("unroll")                                                          \
  for (int j = 0; j < 4; ++j)                                                \
    GLDS(Ab + (size_t)((TS) * 128 + j * 524288) + voff,                      \
         sAc + (BUF) * 32768 + j * 8192 + wbase);

#define STAGEB(BUF, TS)                                                      \
  _Pragma("unroll")                                                          \
  for (int j = 0; j < 4; ++j)                                                \
    GLDS(Bb + (size_t)((TS) * 128 + j * 524288) + voff,                      \
         sBc + (BUF) * 32768 + j * 8192 + wbase);

  // ---- fragment-read geometry (swizzled ds_read) ----
  const int lr = lane & 15;
  const int lk = lane >> 4;
  const int kx0 = (lk << 4) ^ ((lr & 7) << 4);
  const int kx1 = (64 + (lk << 4)) ^ ((lr & 7) << 4);
  const char* const rA0 = sAc + (((wr << 7) + lr) << 7) + kx0;
  const char* const rA1 = sAc + (((wr << 7) + lr) << 7) + kx1;
  const char* const rB0 = sBc + (((wc << 6) + lr) << 7) + kx0;
  const char* const rB1 = sBc + (((wc << 6) + lr) << 7) + kx1;

#define PREFA(DST, BUF, MOFS)                                                \
  _Pragma("unroll")                                                          \
  for (int m = 0; m < 4; ++m) {                                              \
    DST[m][0] = *(const bf16x8*)(rA0 + (BUF) * 32768 + ((MOFS) + m) * 2048); \
    DST[m][1] = *(const bf16x8*)(rA1 + (BUF) * 32768 + ((MOFS) + m) * 2048); \
  }

#define PREFB(DST, BUF, NOFS)                                                \
  _Pragma("unroll")                                                          \
  for (int n = 0; n < 2; ++n) {                                              \
    DST[n][0] = *(const bf16x8*)(rB0 + (BUF) * 32768 + ((NOFS) + n) * 2048); \
    DST[n][1] = *(const bf16x8*)(rB1 + (BUF) * 32768 + ((NOFS) + n) * 2048); \
  }

#define MFMA8X(AF, BF, MB, NB)                                               \
  _Pragma("unroll")                                                          \
  for (int m = 0; m < 4; ++m) {                                              \
    acc[(MB) + m][(NB) + 0] =                                                \
        MFMA_BF16(AF[m][0], BF[0][0], acc[(MB) + m][(NB) + 0], 0, 0, 0);     \
    acc[(MB) + m][(NB) + 0] =                                                \
        MFMA_BF16(AF[m][1], BF[0][1], acc[(MB) + m][(NB) + 0], 0, 0, 0);     \
    acc[(MB) + m][(NB) + 1] =                                                \
        MFMA_BF16(AF[m][0], BF[1][0], acc[(MB) + m][(NB) + 1], 0, 0, 0);     \
    acc[(MB) + m][(NB) + 1] =                                                \
        MFMA_BF16(AF[m][1], BF[1][1], acc[(MB) + m][(NB) + 1], 0, 0, 0);     \
  }

#define SBAR0 __builtin_amdgcn_sched_barrier(0)
#define TILE_SYNC                                                            \
  asm volatile("s_waitcnt lgkmcnt(0) vmcnt(0)" ::: "memory");                \
  SBAR0;                                                                     \
  __builtin_amdgcn_s_barrier();                                              \
  SBAR0;

  // epilogue coords (needed for bias-seeded acc)
  const int er = gm0 + (wr << 7) + ((lane >> 4) << 2);
  const int ec = gn0 + (wc << 6) + (lane & 15);

  f32x4 acc[8][4];
#pragma unroll
  for (int n = 0; n < 4; ++n) {
    const float bv = bias[ec + n * 16];
#pragma unroll
    for (int m = 0; m < 8; ++m) acc[m][n] = (f32x4){bv, bv, bv, bv};
  }

  bf16x8 aX[4][2], aY[4][2], b0[2][2], b2[2][2];

  // ---- prologue: stage tiles 0,1; explicit drain of tile 0; publish; first reads ----
  STAGEA(0, 0) STAGEB(0, 0) STAGEA(1, 1) STAGEB(1, 1)
  asm volatile("s_waitcnt vmcnt(8)" ::: "memory");
  SBAR0;
  __builtin_amdgcn_s_barrier();
  SBAR0;
  PREFA(aX, 0, 0) PREFB(b0, 0, 0)

  // Phase order per tile: P1(m03,n01,aX) P2(m47,n01,aY) P3(m03,n23,aX) P4(m47,n23,aY)
  // Prefetch: P1->aY=A47(t)  P2->b2=B23(t)  P3->b0=B01(t+1)  P4->aX=A03(t+1)
  // Staging:  P3: A(t+2)->BUF (post-sync);  P4: B(t+2)->BUF — skipped on last 2 tiles
#define TILE(BUF, T)                                                         \
  {                                                                          \
    /* P1 */                                                                 \
    PREFA(aY, BUF, 4)                                                        \
    __builtin_amdgcn_s_setprio(1);                                           \
    MFMA8X(aX, b0, 0, 0)                                                     \
    __builtin_amdgcn_s_setprio(0);                                           \
    /* P2 */                                                                 \
    PREFB(b2, BUF, 2)                                                        \
    __builtin_amdgcn_s_setprio(1);                                           \
    MFMA8X(aY, b0, 4, 0)                                                     \
    __builtin_amdgcn_s_setprio(0);                                           \
    /* P3: tile boundary (explicit certify-then-publish) */                  \
    TILE_SYNC                                                                \
    if ((T) + 2 < NT) STAGEA(BUF, (T) + 2)                                   \
    PREFB(b0, (BUF) ^ 1, 0)                                                  \
    __builtin_amdgcn_s_setprio(1);                                           \
    MFMA8X(aX, b2, 0, 2)                                                     \
    __builtin_amdgcn_s_setprio(0);                                           \
    /* P4 */                                                                 \
    if ((T) + 2 < NT) STAGEB(BUF, (T) + 2)                                   \
    PREFA(aX, (BUF) ^ 1, 0)                                                  \
    __builtin_amdgcn_s_setprio(1);                                           \
    MFMA8X(aY, b2, 4, 2)                                                     \
    __builtin_amdgcn_s_setprio(0);                                           \
  }

  for (int t = 0; t < NT; t += 2) {
    TILE(0, t)
    TILE(1, t + 1)
  }
  asm volatile("s_waitcnt vmcnt(0) lgkmcnt(0)" ::: "memory");

  // ---- epilogue: C[row][col] = acc (bias pre-seeded) ----
#pragma unroll
  for (int n = 0; n < 4; ++n) {
    const int c = ec + n * 16;
#pragma unroll
    for (int m = 0; m < 8; ++m) {
#pragma unroll
      for (int j = 0; j < 4; ++j) {
        C[(size_t)(er + m * 16 + j) * N + c] = acc[m][n][j];
      }
    }
  }
}

extern "C" void kernel_launch(void* const* d_in, const int* in_sizes, int n_in,
                              void* d_out, int out_size, void* d_ws, size_t ws_size,
                              hipStream_t stream) {
  const float* x = (const float*)d_in[0];     // [8,2048,4096]
  const float* L = (const float*)d_in[1];     // [64,64,64,8]
  const float* R = (const float*)d_in[2];     // [8,64,64,64]
  const float* bias = (const float*)d_in[3];  // [4096]
  float* out = (float*)d_out;                 // [16384,4096]

  __hip_bfloat16* Wb = (__hip_bfloat16*)d_ws;                                    // 33.5 MB
  __hip_bfloat16* Xb = (__hip_bfloat16*)((char*)d_ws + (size_t)4096 * 4096 * 2); // 134 MB

  k_prep<<<8192, 256, 0, stream>>>(x, Xb, L, R, Wb);

  dim3 grid(1024);  // (16384/256) * (4096/256)
  k_gemm_bt<<<grid, 512, 0, stream>>>(Xb, Wb, bias, out);
}

// Round 17
// 534.326 us; speedup vs baseline: 1.2792x; 1.0467x over previous
//
#include <hip/hip_runtime.h>
#include <hip/hip_bf16.h>

typedef __attribute__((ext_vector_type(8))) short bf16x8;
typedef __attribute__((ext_vector_type(4))) float f32x4;

#define GLDS(g, l) \
  __builtin_amdgcn_global_load_lds((const __attribute__((address_space(1))) void*)(g), \
                                   (__attribute__((address_space(3))) void*)(l), 16, 0, 0)

#define MFMA_BF16 __builtin_amdgcn_mfma_f32_16x16x32_bf16

// ---------------- Kernel 1: fused X fp32->bf16 cvt + W assembly (proven) -------------
__global__ __launch_bounds__(256) void k_prep(const float* __restrict__ x,
                                              __hip_bfloat16* __restrict__ y,
                                              const float* __restrict__ L,
                                              const float* __restrict__ R,
                                              __hip_bfloat16* __restrict__ W) {
  if (blockIdx.x < 4096) {
    // cvt: grid-stride over 8-element groups (memory-roofline bound, ~64 us)
    const long n8 = (long)16384 * 4096 / 8;
    const long stride = (long)4096 * 256;
    for (long i = (long)blockIdx.x * 256 + threadIdx.x; i < n8; i += stride) {
      const float4* xin = reinterpret_cast<const float4*>(x) + i * 2;
      float4 v0 = xin[0];
      float4 v1 = xin[1];
      union { __hip_bfloat16 h[8]; int4 v; } o;
      o.h[0] = __float2bfloat16(v0.x);
      o.h[1] = __float2bfloat16(v0.y);
      o.h[2] = __float2bfloat16(v0.z);
      o.h[3] = __float2bfloat16(v0.w);
      o.h[4] = __float2bfloat16(v1.x);
      o.h[5] = __float2bfloat16(v1.y);
      o.h[6] = __float2bfloat16(v1.z);
      o.h[7] = __float2bfloat16(v1.w);
      *reinterpret_cast<int4*>(y + i * 8) = o.v;
    }
  } else {
    // make_w: one block per (b,c) pair; reads L 2KB + R 2KB (L2/L3-resident)
    const int bc = blockIdx.x - 4096;  // b*64 + c
    const int b = bc >> 6, c = bc & 63;
    const int d = threadIdx.x & 63;
    const int q = threadIdx.x >> 6;
    float Rr[8];
#pragma unroll
    for (int r = 0; r < 8; ++r)
      Rr[r] = R[(((size_t)(r * 64 + b) * 64 + c) << 6) + d];
#pragma unroll 4
    for (int a = q * 16; a < q * 16 + 16; ++a) {
      const float* Lp = L + (((size_t)(a * 64 + b) * 64 + c) << 3);
      float s = 0.f;
#pragma unroll
      for (int r = 0; r < 8; ++r) s = fmaf(Lp[r], Rr[r], s);
      W[((size_t)(a * 64 + b) << 12) + (c << 6) + d] = __float2bfloat16(s);
    }
  }
}

// ---------------- Kernel 2: 256x256 bf16 GEMM (session-best structure) ----------------
// Fence-free phases (compiler-tracked ds_read->MFMA deps); ONE explicit tile boundary
// per K-tile: asm lgkm0+vmcnt0 drain BEFORE s_barrier (certify-then-publish; the
// r5/r6/r11 race lessons), sched_barrier brackets. T1 XCD swizzle + T2 XOR swizzle
// (0 bank conflicts) + T5 setprio. Bias pre-seeded into accumulators.
// NEW r17: non-temporal C stores — keep streaming output from evicting the
// L2/L3-resident Xb/Wb panels (FETCH_SIZE 590 MB vs 167 MB ideal = pollution).
__global__ __launch_bounds__(512, 2) void k_gemm_bt(const __hip_bfloat16* __restrict__ A,
                                                    const __hip_bfloat16* __restrict__ B,
                                                    const float* __restrict__ bias,
                                                    float* __restrict__ C) {
  const int K = 4096, N = 4096, NT = 64;
  __shared__ char lds[131072];
  char* const sAc = lds;          // 2 x 32768: A tile [256][64] bf16, swizzled
  char* const sBc = lds + 65536;  // 2 x 32768

  const int tid = threadIdx.x;
  const int lane = tid & 63;
  const int wid = tid >> 6;
  const int wr = wid >> 2;    // 0..1 (M half)
  const int wc = wid & 3;     // 0..3 (N quarter)

  // T1: bijective XCD swizzle (nwg = 1024, divisible by 8)
  const int orig = blockIdx.x;
  const int wg = (orig & 7) * 128 + (orig >> 3);
  const int gm0 = (wg >> 4) * 256;
  const int gn0 = (wg & 15) * 256;

  // ---- staging geometry (pre-swizzled global source, linear LDS dest) ----
  const int crow = tid >> 3;
  const int scol = ((tid & 7) << 4) ^ ((crow & 7) << 4);
  const int voff = crow * 8192 + scol;
  const int wbase = (tid >> 6) << 10;
  const char* const Ab = (const char*)(A + (size_t)gm0 * K);
  const char* const Bb = (const char*)(B + (size_t)gn0 * K);

#define STAGEA(BUF, TS)                                                      \
  _Pragma("unroll")                                                          \
  for (int j = 0; j < 4; ++j)                                                \
    GLDS(Ab + (size_t)((TS) * 128 + j * 524288) + voff,                      \
         sAc + (BUF) * 32768 + j * 8192 + wbase);

#define STAGEB(BUF, TS)                                                      \
  _Pragma("unroll")                                                          \
  for (int j = 0; j < 4; ++j)                                                \
    GLDS(Bb + (size_t)((TS) * 128 + j * 524288) + voff,                      \
         sBc + (BUF) * 32768 + j * 8192 + wbase);

  // ---- fragment-read geometry (swizzled ds_read) ----
  const int lr = lane & 15;
  const int lk = lane >> 4;
  const int kx0 = (lk << 4) ^ ((lr & 7) << 4);
  const int kx1 = (64 + (lk << 4)) ^ ((lr & 7) << 4);
  const char* const rA0 = sAc + (((wr << 7) + lr) << 7) + kx0;
  const char* const rA1 = sAc + (((wr << 7) + lr) << 7) + kx1;
  const char* const rB0 = sBc + (((wc << 6) + lr) << 7) + kx0;
  const char* const rB1 = sBc + (((wc << 6) + lr) << 7) + kx1;

#define PREFA(DST, BUF, MOFS)                                                \
  _Pragma("unroll")                                                          \
  for (int m = 0; m < 4; ++m) {                                              \
    DST[m][0] = *(const bf16x8*)(rA0 + (BUF) * 32768 + ((MOFS) + m) * 2048); \
    DST[m][1] = *(const bf16x8*)(rA1 + (BUF) * 32768 + ((MOFS) + m) * 2048); \
  }

#define PREFB(DST, BUF, NOFS)                                                \
  _Pragma("unroll")                                                          \
  for (int n = 0; n < 2; ++n) {                                              \
    DST[n][0] = *(const bf16x8*)(rB0 + (BUF) * 32768 + ((NOFS) + n) * 2048); \
    DST[n][1] = *(const bf16x8*)(rB1 + (BUF) * 32768 + ((NOFS) + n) * 2048); \
  }

#define MFMA8X(AF, BF, MB, NB)                                               \
  _Pragma("unroll")                                                          \
  for (int m = 0; m < 4; ++m) {                                              \
    acc[(MB) + m][(NB) + 0] =                                                \
        MFMA_BF16(AF[m][0], BF[0][0], acc[(MB) + m][(NB) + 0], 0, 0, 0);     \
    acc[(MB) + m][(NB) + 0] =                                                \
        MFMA_BF16(AF[m][1], BF[0][1], acc[(MB) + m][(NB) + 0], 0, 0, 0);     \
    acc[(MB) + m][(NB) + 1] =                                                \
        MFMA_BF16(AF[m][0], BF[1][0], acc[(MB) + m][(NB) + 1], 0, 0, 0);     \
    acc[(MB) + m][(NB) + 1] =                                                \
        MFMA_BF16(AF[m][1], BF[1][1], acc[(MB) + m][(NB) + 1], 0, 0, 0);     \
  }

#define SBAR0 __builtin_amdgcn_sched_barrier(0)
#define TILE_SYNC                                                            \
  asm volatile("s_waitcnt lgkmcnt(0) vmcnt(0)" ::: "memory");                \
  SBAR0;                                                                     \
  __builtin_amdgcn_s_barrier();                                              \
  SBAR0;

  // epilogue coords (needed for bias-seeded acc)
  const int er = gm0 + (wr << 7) + ((lane >> 4) << 2);
  const int ec = gn0 + (wc << 6) + (lane & 15);

  f32x4 acc[8][4];
#pragma unroll
  for (int n = 0; n < 4; ++n) {
    const float bv = bias[ec + n * 16];
#pragma unroll
    for (int m = 0; m < 8; ++m) acc[m][n] = (f32x4){bv, bv, bv, bv};
  }

  bf16x8 aX[4][2], aY[4][2], b0[2][2], b2[2][2];

  // ---- prologue: stage tiles 0,1; explicit drain of tile 0; publish; first reads ----
  STAGEA(0, 0) STAGEB(0, 0) STAGEA(1, 1) STAGEB(1, 1)
  asm volatile("s_waitcnt vmcnt(8)" ::: "memory");
  SBAR0;
  __builtin_amdgcn_s_barrier();
  SBAR0;
  PREFA(aX, 0, 0) PREFB(b0, 0, 0)

  // Phase order per tile: P1(m03,n01,aX) P2(m47,n01,aY) P3(m03,n23,aX) P4(m47,n23,aY)
  // Prefetch: P1->aY=A47(t)  P2->b2=B23(t)  P3->b0=B01(t+1)  P4->aX=A03(t+1)
  // Staging:  P3: A(t+2)->BUF (post-sync);  P4: B(t+2)->BUF — skipped on last 2 tiles
#define TILE(BUF, T)                                                         \
  {                                                                          \
    /* P1 */                                                                 \
    PREFA(aY, BUF, 4)                                                        \
    __builtin_amdgcn_s_setprio(1);                                           \
    MFMA8X(aX, b0, 0, 0)                                                     \
    __builtin_amdgcn_s_setprio(0);                                           \
    /* P2 */                                                                 \
    PREFB(b2, BUF, 2)                                                        \
    __builtin_amdgcn_s_setprio(1);                                           \
    MFMA8X(aY, b0, 4, 0)                                                     \
    __builtin_amdgcn_s_setprio(0);                                           \
    /* P3: tile boundary (explicit certify-then-publish) */                  \
    TILE_SYNC                                                                \
    if ((T) + 2 < NT) STAGEA(BUF, (T) + 2)                                   \
    PREFB(b0, (BUF) ^ 1, 0)                                                  \
    __builtin_amdgcn_s_setprio(1);                                           \
    MFMA8X(aX, b2, 0, 2)                                                     \
    __builtin_amdgcn_s_setprio(0);                                           \
    /* P4 */                                                                 \
    if ((T) + 2 < NT) STAGEB(BUF, (T) + 2)                                   \
    PREFA(aX, (BUF) ^ 1, 0)                                                  \
    __builtin_amdgcn_s_setprio(1);                                           \
    MFMA8X(aY, b2, 4, 2)                                                     \
    __builtin_amdgcn_s_setprio(0);                                           \
  }

  for (int t = 0; t < NT; t += 2) {
    TILE(0, t)
    TILE(1, t + 1)
  }
  asm volatile("s_waitcnt vmcnt(0) lgkmcnt(0)" ::: "memory");

  // ---- epilogue: C[row][col] = acc (bias pre-seeded), NON-TEMPORAL stores ----
  // C is written once and never re-read by the GPU: nt stores avoid L2/L3
  // write-allocate pollution that evicts the cache-resident A/B panels.
#pragma unroll
  for (int n = 0; n < 4; ++n) {
    const int c = ec + n * 16;
#pragma unroll
    for (int m = 0; m < 8; ++m) {
#pragma unroll
      for (int j = 0; j < 4; ++j) {
        __builtin_nontemporal_store(acc[m][n][j], &C[(size_t)(er + m * 16 + j) * N + c]);
      }
    }
  }
}

extern "C" void kernel_launch(void* const* d_in, const int* in_sizes, int n_in,
                              void* d_out, int out_size, void* d_ws, size_t ws_size,
                              hipStream_t stream) {
  const float* x = (const float*)d_in[0];     // [8,2048,4096]
  const float* L = (const float*)d_in[1];     // [64,64,64,8]
  const float* R = (const float*)d_in[2];     // [8,64,64,64]
  const float* bias = (const float*)d_in[3];  // [4096]
  float* out = (float*)d_out;                 // [16384,4096]

  __hip_bfloat16* Wb = (__hip_bfloat16*)d_ws;                                    // 33.5 MB
  __hip_bfloat16* Xb = (__hip_bfloat16*)((char*)d_ws + (size_t)4096 * 4096 * 2); // 134 MB

  k_prep<<<8192, 256, 0, stream>>>(x, Xb, L, R, Wb);

  dim3 grid(1024);  // (16384/256) * (4096/256)
  k_gemm_bt<<<grid, 512, 0, stream>>>(Xb, Wb, bias, out);
}

// Round 19
// 507.622 us; speedup vs baseline: 1.3465x; 1.0526x over previous
//
#include <hip/hip_runtime.h>
#include <hip/hip_bf16.h>

typedef __attribute__((ext_vector_type(8))) short bf16x8;
typedef __attribute__((ext_vector_type(4))) float f32x4;

#define GLDS(g, l) \
  __builtin_amdgcn_global_load_lds((const __attribute__((address_space(1))) void*)(g), \
                                   (__attribute__((address_space(3))) void*)(l), 16, 0, 0)

#define MFMA_BF16 __builtin_amdgcn_mfma_f32_16x16x32_bf16

// ---------------- Kernel 1: fused X fp32->bf16 cvt + W assembly ----------------------
// r19: single-use inputs (x, L) loaded NON-TEMPORAL (via native ext_vector f32x4 —
// __builtin_nontemporal_load rejects HIP_vector_type) so the 268 MB x-stream doesn't
// evict the Xb/Wb panels the GEMM is about to read from L3. Xb/Wb writes stay
// cacheable (they ARE re-read).
__global__ __launch_bounds__(256) void k_prep(const float* __restrict__ x,
                                              __hip_bfloat16* __restrict__ y,
                                              const float* __restrict__ L,
                                              const float* __restrict__ R,
                                              __hip_bfloat16* __restrict__ W) {
  if (blockIdx.x < 4096) {
    // cvt: grid-stride over 8-element groups (memory-roofline bound, ~64 us)
    const long n8 = (long)16384 * 4096 / 8;
    const long stride = (long)4096 * 256;
    for (long i = (long)blockIdx.x * 256 + threadIdx.x; i < n8; i += stride) {
      const f32x4* xin = reinterpret_cast<const f32x4*>(x) + i * 2;
      f32x4 v0 = __builtin_nontemporal_load(xin);
      f32x4 v1 = __builtin_nontemporal_load(xin + 1);
      union { __hip_bfloat16 h[8]; int4 v; } o;
      o.h[0] = __float2bfloat16(v0[0]);
      o.h[1] = __float2bfloat16(v0[1]);
      o.h[2] = __float2bfloat16(v0[2]);
      o.h[3] = __float2bfloat16(v0[3]);
      o.h[4] = __float2bfloat16(v1[0]);
      o.h[5] = __float2bfloat16(v1[1]);
      o.h[6] = __float2bfloat16(v1[2]);
      o.h[7] = __float2bfloat16(v1[3]);
      *reinterpret_cast<int4*>(y + i * 8) = o.v;
    }
  } else {
    // make_w: one block per (b,c) pair; reads L 2KB (nt, single-use) + R 2KB
    const int bc = blockIdx.x - 4096;  // b*64 + c
    const int b = bc >> 6, c = bc & 63;
    const int d = threadIdx.x & 63;
    const int q = threadIdx.x >> 6;
    float Rr[8];
#pragma unroll
    for (int r = 0; r < 8; ++r)
      Rr[r] = R[(((size_t)(r * 64 + b) * 64 + c) << 6) + d];
#pragma unroll 4
    for (int a = q * 16; a < q * 16 + 16; ++a) {
      const float* Lp = L + (((size_t)(a * 64 + b) * 64 + c) << 3);
      float s = 0.f;
#pragma unroll
      for (int r = 0; r < 8; ++r) s = fmaf(__builtin_nontemporal_load(Lp + r), Rr[r], s);
      W[((size_t)(a * 64 + b) << 12) + (c << 6) + d] = __float2bfloat16(s);
    }
  }
}

// ---------------- Kernel 2: 256x256 bf16 GEMM (session-best structure, r17) ----------
// Fence-free phases (compiler-tracked ds_read->MFMA deps); ONE explicit tile boundary
// per K-tile: asm lgkm0+vmcnt0 drain BEFORE s_barrier (certify-then-publish; the
// r5/r6/r11 race lessons), sched_barrier brackets. T1 XCD swizzle + T2 XOR swizzle
// (0 bank conflicts) + T5 setprio. Bias pre-seeded into acc. Non-temporal C stores
// (r17: +25 us — write-path relief).
__global__ __launch_bounds__(512, 2) void k_gemm_bt(const __hip_bfloat16* __restrict__ A,
                                                    const __hip_bfloat16* __restrict__ B,
                                                    const float* __restrict__ bias,
                                                    float* __restrict__ C) {
  const int K = 4096, N = 4096, NT = 64;
  __shared__ char lds[131072];
  char* const sAc = lds;          // 2 x 32768: A tile [256][64] bf16, swizzled
  char* const sBc = lds + 65536;  // 2 x 32768

  const int tid = threadIdx.x;
  const int lane = tid & 63;
  const int wid = tid >> 6;
  const int wr = wid >> 2;    // 0..1 (M half)
  const int wc = wid & 3;     // 0..3 (N quarter)

  // T1: bijective XCD swizzle (nwg = 1024, divisible by 8)
  const int orig = blockIdx.x;
  const int wg = (orig & 7) * 128 + (orig >> 3);
  const int gm0 = (wg >> 4) * 256;
  const int gn0 = (wg & 15) * 256;

  // ---- staging geometry (pre-swizzled global source, linear LDS dest) ----
  const int crow = tid >> 3;
  const int scol = ((tid & 7) << 4) ^ ((crow & 7) << 4);
  const int voff = crow * 8192 + scol;
  const int wbase = (tid >> 6) << 10;
  const char* const Ab = (const char*)(A + (size_t)gm0 * K);
  const char* const Bb = (const char*)(B + (size_t)gn0 * K);

#define STAGEA(BUF, TS)                                                      \
  _Pragma("unroll")                                                          \
  for (int j = 0; j < 4; ++j)                                                \
    GLDS(Ab + (size_t)((TS) * 128 + j * 524288) + voff,                      \
         sAc + (BUF) * 32768 + j * 8192 + wbase);

#define STAGEB(BUF, TS)                                                      \
  _Pragma("unroll")                                                          \
  for (int j = 0; j < 4; ++j)                                                \
    GLDS(Bb + (size_t)((TS) * 128 + j * 524288) + voff,                      \
         sBc + (BUF) * 32768 + j * 8192 + wbase);

  // ---- fragment-read geometry (swizzled ds_read) ----
  const int lr = lane & 15;
  const int lk = lane >> 4;
  const int kx0 = (lk << 4) ^ ((lr & 7) << 4);
  const int kx1 = (64 + (lk << 4)) ^ ((lr & 7) << 4);
  const char* const rA0 = sAc + (((wr << 7) + lr) << 7) + kx0;
  const char* const rA1 = sAc + (((wr << 7) + lr) << 7) + kx1;
  const char* const rB0 = sBc + (((wc << 6) + lr) << 7) + kx0;
  const char* const rB1 = sBc + (((wc << 6) + lr) << 7) + kx1;

#define PREFA(DST, BUF, MOFS)                                                \
  _Pragma("unroll")                                                          \
  for (int m = 0; m < 4; ++m) {                                              \
    DST[m][0] = *(const bf16x8*)(rA0 + (BUF) * 32768 + ((MOFS) + m) * 2048); \
    DST[m][1] = *(const bf16x8*)(rA1 + (BUF) * 32768 + ((MOFS) + m) * 2048); \
  }

#define PREFB(DST, BUF, NOFS)                                                \
  _Pragma("unroll")                                                          \
  for (int n = 0; n < 2; ++n) {                                              \
    DST[n][0] = *(const bf16x8*)(rB0 + (BUF) * 32768 + ((NOFS) + n) * 2048); \
    DST[n][1] = *(const bf16x8*)(rB1 + (BUF) * 32768 + ((NOFS) + n) * 2048); \
  }

#define MFMA8X(AF, BF, MB, NB)                                               \
  _Pragma("unroll")                                                          \
  for (int m = 0; m < 4; ++m) {                                              \
    acc[(MB) + m][(NB) + 0] =                                                \
        MFMA_BF16(AF[m][0], BF[0][0], acc[(MB) + m][(NB) + 0], 0, 0, 0);     \
    acc[(MB) + m][(NB) + 0] =                                                \
        MFMA_BF16(AF[m][1], BF[0][1], acc[(MB) + m][(NB) + 0], 0, 0, 0);     \
    acc[(MB) + m][(NB) + 1] =                                                \
        MFMA_BF16(AF[m][0], BF[1][0], acc[(MB) + m][(NB) + 1], 0, 0, 0);     \
    acc[(MB) + m][(NB) + 1] =                                                \
        MFMA_BF16(AF[m][1], BF[1][1], acc[(MB) + m][(NB) + 1], 0, 0, 0);     \
  }

#define SBAR0 __builtin_amdgcn_sched_barrier(0)
#define TILE_SYNC                                                            \
  asm volatile("s_waitcnt lgkmcnt(0) vmcnt(0)" ::: "memory");                \
  SBAR0;                                                                     \
  __builtin_amdgcn_s_barrier();                                              \
  SBAR0;

  // epilogue coords (needed for bias-seeded acc)
  const int er = gm0 + (wr << 7) + ((lane >> 4) << 2);
  const int ec = gn0 + (wc << 6) + (lane & 15);

  f32x4 acc[8][4];
#pragma unroll
  for (int n = 0; n < 4; ++n) {
    const float bv = bias[ec + n * 16];
#pragma unroll
    for (int m = 0; m < 8; ++m) acc[m][n] = (f32x4){bv, bv, bv, bv};
  }

  bf16x8 aX[4][2], aY[4][2], b0[2][2], b2[2][2];

  // ---- prologue: stage tiles 0,1; explicit drain of tile 0; publish; first reads ----
  STAGEA(0, 0) STAGEB(0, 0) STAGEA(1, 1) STAGEB(1, 1)
  asm volatile("s_waitcnt vmcnt(8)" ::: "memory");
  SBAR0;
  __builtin_amdgcn_s_barrier();
  SBAR0;
  PREFA(aX, 0, 0) PREFB(b0, 0, 0)

  // Phase order per tile: P1(m03,n01,aX) P2(m47,n01,aY) P3(m03,n23,aX) P4(m47,n23,aY)
  // Prefetch: P1->aY=A47(t)  P2->b2=B23(t)  P3->b0=B01(t+1)  P4->aX=A03(t+1)
  // Staging:  P3: A(t+2)->BUF (post-sync);  P4: B(t+2)->BUF — skipped on last 2 tiles
#define TILE(BUF, T)                                                         \
  {                                                                          \
    /* P1 */                                                                 \
    PREFA(aY, BUF, 4)                                                        \
    __builtin_amdgcn_s_setprio(1);                                           \
    MFMA8X(aX, b0, 0, 0)                                                     \
    __builtin_amdgcn_s_setprio(0);                                           \
    /* P2 */                                                                 \
    PREFB(b2, BUF, 2)                                                        \
    __builtin_amdgcn_s_setprio(1);                                           \
    MFMA8X(aY, b0, 4, 0)                                                     \
    __builtin_amdgcn_s_setprio(0);                                           \
    /* P3: tile boundary (explicit certify-then-publish) */                  \
    TILE_SYNC                                                                \
    if ((T) + 2 < NT) STAGEA(BUF, (T) + 2)                                   \
    PREFB(b0, (BUF) ^ 1, 0)                                                  \
    __builtin_amdgcn_s_setprio(1);                                           \
    MFMA8X(aX, b2, 0, 2)                                                     \
    __builtin_amdgcn_s_setprio(0);                                           \
    /* P4 */                                                                 \
    if ((T) + 2 < NT) STAGEB(BUF, (T) + 2)                                   \
    PREFA(aX, (BUF) ^ 1, 0)                                                  \
    __builtin_amdgcn_s_setprio(1);                                           \
    MFMA8X(aY, b2, 4, 2)                                                     \
    __builtin_amdgcn_s_setprio(0);                                           \
  }

  for (int t = 0; t < NT; t += 2) {
    TILE(0, t)
    TILE(1, t + 1)
  }
  asm volatile("s_waitcnt vmcnt(0) lgkmcnt(0)" ::: "memory");

  // ---- epilogue: C[row][col] = acc (bias pre-seeded), NON-TEMPORAL stores ----
#pragma unroll
  for (int n = 0; n < 4; ++n) {
    const int c = ec + n * 16;
#pragma unroll
    for (int m = 0; m < 8; ++m) {
#pragma unroll
      for (int j = 0; j < 4; ++j) {
        __builtin_nontemporal_store(acc[m][n][j], &C[(size_t)(er + m * 16 + j) * N + c]);
      }
    }
  }
}

extern "C" void kernel_launch(void* const* d_in, const int* in_sizes, int n_in,
                              void* d_out, int out_size, void* d_ws, size_t ws_size,
                              hipStream_t stream) {
  const float* x = (const float*)d_in[0];     // [8,2048,4096]
  const float* L = (const float*)d_in[1];     // [64,64,64,8]
  const float* R = (const float*)d_in[2];     // [8,64,64,64]
  const float* bias = (const float*)d_in[3];  // [4096]
  float* out = (float*)d_out;                 // [16384,4096]

  __hip_bfloat16* Wb = (__hip_bfloat16*)d_ws;                                    // 33.5 MB
  __hip_bfloat16* Xb = (__hip_bfloat16*)((char*)d_ws + (size_t)4096 * 4096 * 2); // 134 MB

  k_prep<<<8192, 256, 0, stream>>>(x, Xb, L, R, Wb);

  dim3 grid(1024);  // (16384/256) * (4096/256)
  k_gemm_bt<<<grid, 512, 0, stream>>>(Xb, Wb, bias, out);
}

// Round 20
// 502.368 us; speedup vs baseline: 1.3606x; 1.0105x over previous
//
#include <hip/hip_runtime.h>
#include <hip/hip_bf16.h>

typedef __attribute__((ext_vector_type(8))) short bf16x8;
typedef __attribute__((ext_vector_type(4))) float f32x4;

#define GLDS(g, l) \
  __builtin_amdgcn_global_load_lds((const __attribute__((address_space(1))) void*)(g), \
                                   (__attribute__((address_space(3))) void*)(l), 16, 0, 0)

#define MFMA_BF16 __builtin_amdgcn_mfma_f32_16x16x32_bf16

// ---------------- Kernel 1: fused X fp32->bf16 cvt + W assembly (r19-proven) ---------
__global__ __launch_bounds__(256) void k_prep(const float* __restrict__ x,
                                              __hip_bfloat16* __restrict__ y,
                                              const float* __restrict__ L,
                                              const float* __restrict__ R,
                                              __hip_bfloat16* __restrict__ W) {
  if (blockIdx.x < 4096) {
    // cvt: grid-stride over 8-element groups; x is single-use -> non-temporal loads
    const long n8 = (long)16384 * 4096 / 8;
    const long stride = (long)4096 * 256;
    for (long i = (long)blockIdx.x * 256 + threadIdx.x; i < n8; i += stride) {
      const f32x4* xin = reinterpret_cast<const f32x4*>(x) + i * 2;
      f32x4 v0 = __builtin_nontemporal_load(xin);
      f32x4 v1 = __builtin_nontemporal_load(xin + 1);
      union { __hip_bfloat16 h[8]; int4 v; } o;
      o.h[0] = __float2bfloat16(v0[0]);
      o.h[1] = __float2bfloat16(v0[1]);
      o.h[2] = __float2bfloat16(v0[2]);
      o.h[3] = __float2bfloat16(v0[3]);
      o.h[4] = __float2bfloat16(v1[0]);
      o.h[5] = __float2bfloat16(v1[1]);
      o.h[6] = __float2bfloat16(v1[2]);
      o.h[7] = __float2bfloat16(v1[3]);
      *reinterpret_cast<int4*>(y + i * 8) = o.v;
    }
  } else {
    // make_w: one block per (b,c) pair; reads L 2KB (nt, single-use) + R 2KB
    const int bc = blockIdx.x - 4096;  // b*64 + c
    const int b = bc >> 6, c = bc & 63;
    const int d = threadIdx.x & 63;
    const int q = threadIdx.x >> 6;
    float Rr[8];
#pragma unroll
    for (int r = 0; r < 8; ++r)
      Rr[r] = R[(((size_t)(r * 64 + b) * 64 + c) << 6) + d];
#pragma unroll 4
    for (int a = q * 16; a < q * 16 + 16; ++a) {
      const float* Lp = L + (((size_t)(a * 64 + b) * 64 + c) << 3);
      float s = 0.f;
#pragma unroll
      for (int r = 0; r < 8; ++r) s = fmaf(__builtin_nontemporal_load(Lp + r), Rr[r], s);
      W[((size_t)(a * 64 + b) << 12) + (c << 6) + d] = __float2bfloat16(s);
    }
  }
}

// ---------------- Kernel 2: 256x256 bf16 GEMM (session-best K-loop, r12/r17/r19) -----
// Fence-free phases; ONE explicit tile boundary per K-tile (asm lgkm0+vmcnt0 drain
// BEFORE s_barrier — certify-then-publish). T1 + T2 (0 conflicts) + T5. Bias seeded
// into acc. r17: nt C stores. NEW r20: LDS-transposed epilogue — per-wave private
// 16x272B slab, f32x4 nt stores (256B dense segments, 4x fewer store instrs).
__global__ __launch_bounds__(512, 2) void k_gemm_bt(const __hip_bfloat16* __restrict__ A,
                                                    const __hip_bfloat16* __restrict__ B,
                                                    const float* __restrict__ bias,
                                                    float* __restrict__ C) {
  const int K = 4096, N = 4096, NT = 64;
  __shared__ char lds[131072];
  char* const sAc = lds;          // 2 x 32768: A tile [256][64] bf16, swizzled
  char* const sBc = lds + 65536;  // 2 x 32768

  const int tid = threadIdx.x;
  const int lane = tid & 63;
  const int wid = tid >> 6;
  const int wr = wid >> 2;    // 0..1 (M half)
  const int wc = wid & 3;     // 0..3 (N quarter)

  // T1: bijective XCD swizzle (nwg = 1024, divisible by 8)
  const int orig = blockIdx.x;
  const int wg = (orig & 7) * 128 + (orig >> 3);
  const int gm0 = (wg >> 4) * 256;
  const int gn0 = (wg & 15) * 256;

  // ---- staging geometry (pre-swizzled global source, linear LDS dest) ----
  const int crow = tid >> 3;
  const int scol = ((tid & 7) << 4) ^ ((crow & 7) << 4);
  const int voff = crow * 8192 + scol;
  const int wbase = (tid >> 6) << 10;
  const char* const Ab = (const char*)(A + (size_t)gm0 * K);
  const char* const Bb = (const char*)(B + (size_t)gn0 * K);

#define STAGEA(BUF, TS)                                                      \
  _Pragma("unroll")                                                          \
  for (int j = 0; j < 4; ++j)                                                \
    GLDS(Ab + (size_t)((TS) * 128 + j * 524288) + voff,                      \
         sAc + (BUF) * 32768 + j * 8192 + wbase);

#define STAGEB(BUF, TS)                                                      \
  _Pragma("unroll")                                                          \
  for (int j = 0; j < 4; ++j)                                                \
    GLDS(Bb + (size_t)((TS) * 128 + j * 524288) + voff,                      \
         sBc + (BUF) * 32768 + j * 8192 + wbase);

  // ---- fragment-read geometry (swizzled ds_read) ----
  const int lr = lane & 15;
  const int lk = lane >> 4;
  const int kx0 = (lk << 4) ^ ((lr & 7) << 4);
  const int kx1 = (64 + (lk << 4)) ^ ((lr & 7) << 4);
  const char* const rA0 = sAc + (((wr << 7) + lr) << 7) + kx0;
  const char* const rA1 = sAc + (((wr << 7) + lr) << 7) + kx1;
  const char* const rB0 = sBc + (((wc << 6) + lr) << 7) + kx0;
  const char* const rB1 = sBc + (((wc << 6) + lr) << 7) + kx1;

#define PREFA(DST, BUF, MOFS)                                                \
  _Pragma("unroll")                                                          \
  for (int m = 0; m < 4; ++m) {                                              \
    DST[m][0] = *(const bf16x8*)(rA0 + (BUF) * 32768 + ((MOFS) + m) * 2048); \
    DST[m][1] = *(const bf16x8*)(rA1 + (BUF) * 32768 + ((MOFS) + m) * 2048); \
  }

#define PREFB(DST, BUF, NOFS)                                                \
  _Pragma("unroll")                                                          \
  for (int n = 0; n < 2; ++n) {                                              \
    DST[n][0] = *(const bf16x8*)(rB0 + (BUF) * 32768 + ((NOFS) + n) * 2048); \
    DST[n][1] = *(const bf16x8*)(rB1 + (BUF) * 32768 + ((NOFS) + n) * 2048); \
  }

#define MFMA8X(AF, BF, MB, NB)                                               \
  _Pragma("unroll")                                                          \
  for (int m = 0; m < 4; ++m) {                                              \
    acc[(MB) + m][(NB) + 0] =                                                \
        MFMA_BF16(AF[m][0], BF[0][0], acc[(MB) + m][(NB) + 0], 0, 0, 0);     \
    acc[(MB) + m][(NB) + 0] =                                                \
        MFMA_BF16(AF[m][1], BF[0][1], acc[(MB) + m][(NB) + 0], 0, 0, 0);     \
    acc[(MB) + m][(NB) + 1] =                                                \
        MFMA_BF16(AF[m][0], BF[1][0], acc[(MB) + m][(NB) + 1], 0, 0, 0);     \
    acc[(MB) + m][(NB) + 1] =                                                \
        MFMA_BF16(AF[m][1], BF[1][1], acc[(MB) + m][(NB) + 1], 0, 0, 0);     \
  }

#define SBAR0 __builtin_amdgcn_sched_barrier(0)
#define TILE_SYNC                                                            \
  asm volatile("s_waitcnt lgkmcnt(0) vmcnt(0)" ::: "memory");                \
  SBAR0;                                                                     \
  __builtin_amdgcn_s_barrier();                                              \
  SBAR0;

  // epilogue coords (needed for bias-seeded acc)
  const int ec = gn0 + (wc << 6) + lr;

  f32x4 acc[8][4];
#pragma unroll
  for (int n = 0; n < 4; ++n) {
    const float bv = bias[ec + n * 16];
#pragma unroll
    for (int m = 0; m < 8; ++m) acc[m][n] = (f32x4){bv, bv, bv, bv};
  }

  bf16x8 aX[4][2], aY[4][2], b0[2][2], b2[2][2];

  // ---- prologue: stage tiles 0,1; explicit drain of tile 0; publish; first reads ----
  STAGEA(0, 0) STAGEB(0, 0) STAGEA(1, 1) STAGEB(1, 1)
  asm volatile("s_waitcnt vmcnt(8)" ::: "memory");
  SBAR0;
  __builtin_amdgcn_s_barrier();
  SBAR0;
  PREFA(aX, 0, 0) PREFB(b0, 0, 0)

  // Phase order per tile: P1(m03,n01,aX) P2(m47,n01,aY) P3(m03,n23,aX) P4(m47,n23,aY)
  // Prefetch: P1->aY=A47(t)  P2->b2=B23(t)  P3->b0=B01(t+1)  P4->aX=A03(t+1)
  // Staging:  P3: A(t+2)->BUF (post-sync);  P4: B(t+2)->BUF — skipped on last 2 tiles
#define TILE(BUF, T)                                                         \
  {                                                                          \
    /* P1 */                                                                 \
    PREFA(aY, BUF, 4)                                                        \
    __builtin_amdgcn_s_setprio(1);                                           \
    MFMA8X(aX, b0, 0, 0)                                                     \
    __builtin_amdgcn_s_setprio(0);                                           \
    /* P2 */                                                                 \
    PREFB(b2, BUF, 2)                                                        \
    __builtin_amdgcn_s_setprio(1);                                           \
    MFMA8X(aY, b0, 4, 0)                                                     \
    __builtin_amdgcn_s_setprio(0);                                           \
    /* P3: tile boundary (explicit certify-then-publish) */                  \
    TILE_SYNC                                                                \
    if ((T) + 2 < NT) STAGEA(BUF, (T) + 2)                                   \
    PREFB(b0, (BUF) ^ 1, 0)                                                  \
    __builtin_amdgcn_s_setprio(1);                                           \
    MFMA8X(aX, b2, 0, 2)                                                     \
    __builtin_amdgcn_s_setprio(0);                                           \
    /* P4 */                                                                 \
    if ((T) + 2 < NT) STAGEB(BUF, (T) + 2)                                   \
    PREFA(aX, (BUF) ^ 1, 0)                                                  \
    __builtin_amdgcn_s_setprio(1);                                           \
    MFMA8X(aY, b2, 4, 2)                                                     \
    __builtin_amdgcn_s_setprio(0);                                           \
  }

  for (int t = 0; t < NT; t += 2) {
    TILE(0, t)
    TILE(1, t + 1)
  }
  asm volatile("s_waitcnt vmcnt(0) lgkmcnt(0)" ::: "memory");
  SBAR0;

  // ---- epilogue: LDS-transposed coalesced nt stores ----
  // Per-wave PRIVATE slab: 16 rows x 272B (64 fp32 + 16B pad -> 2-way banks, free).
  // Write acc scatter into slab, lgkm-drain, read f32x4 rows, nt-store 16B/lane
  // (256B dense row segments). Slab regions only alias other waves' junk-destined
  // K-loop reads (values never consumed) — race-free.
  char* const slab = lds + wid * 4352;
  const int R0 = gm0 + (wr << 7);
  const int Cc0 = gn0 + (wc << 6);
#pragma unroll
  for (int m = 0; m < 8; ++m) {
#pragma unroll
    for (int n = 0; n < 4; ++n) {
#pragma unroll
      for (int j = 0; j < 4; ++j) {
        *(float*)(slab + ((lk << 2) + j) * 272 + (((n << 4) + lr) << 2)) = acc[m][n][j];
      }
    }
    asm volatile("s_waitcnt lgkmcnt(0)" ::: "memory");
    SBAR0;
#pragma unroll
    for (int p = 0; p < 4; ++p) {
      f32x4 v = *(const f32x4*)(slab + ((p << 2) + lk) * 272 + (lr << 4));
      __builtin_nontemporal_store(
          v, (f32x4*)&C[(size_t)(R0 + (m << 4) + (p << 2) + lk) * N + Cc0 + (lr << 2)]);
    }
    asm volatile("s_waitcnt lgkmcnt(0)" ::: "memory");
    SBAR0;
  }
}

extern "C" void kernel_launch(void* const* d_in, const int* in_sizes, int n_in,
                              void* d_out, int out_size, void* d_ws, size_t ws_size,
                              hipStream_t stream) {
  const float* x = (const float*)d_in[0];     // [8,2048,4096]
  const float* L = (const float*)d_in[1];     // [64,64,64,8]
  const float* R = (const float*)d_in[2];     // [8,64,64,64]
  const float* bias = (const float*)d_in[3];  // [4096]
  float* out = (float*)d_out;                 // [16384,4096]

  __hip_bfloat16* Wb = (__hip_bfloat16*)d_ws;                                    // 33.5 MB
  __hip_bfloat16* Xb = (__hip_bfloat16*)((char*)d_ws + (size_t)4096 * 4096 * 2); // 134 MB

  k_prep<<<8192, 256, 0, stream>>>(x, Xb, L, R, Wb);

  dim3 grid(1024);  // (16384/256) * (4096/256)
  k_gemm_bt<<<grid, 512, 0, stream>>>(Xb, Wb, bias, out);
}